// Round 16
// baseline (39.998 us; speedup 1.0000x reference)
//
#include <hip/hip_runtime.h>

#define NEG_SLOPE 0.2f
#define TPB    256
#define NB     256              // dst buckets
#define CNT    196              // nodes per bucket (NB*CNT >= N)
#define EBLK   256              // edge blocks (== TPB: agg thread t <-> eblk t)
#define ER     4                // rounds: ER*TPB >= ceil(E/EBLK) (1024 >= 782)
#define MAGIC  21913099ULL      // ceil(2^32/196): exact d/196 for d < 39M
#define NBLK2  782              // node blocks: 782*16=12512 groups, x4 sweeps
#define CHUNKCAP 1024           // slots per eblk record chunk (>= 782)
#define PSTRIDE  260            // cntP row stride (256 prefixes + total + pad)

__device__ __forceinline__ float wsum64(float v) {
#pragma unroll
    for (int off = 1; off < 64; off <<= 1) v += __shfl_xor(v, off);
    return v;
}

// ---------------------------------------------------------------------------
// K_fold: fold W_lin through W_out/att_src/att_dst (GAT output is linear in
// h -> h never materialized), W_edge through att_edge, bias_conv+b_out.
// ---------------------------------------------------------------------------
__global__ __launch_bounds__(TPB) void k_fold(
        const float* __restrict__ Wlin, const float* __restrict__ att_src,
        const float* __restrict__ att_dst, const float* __restrict__ Wedge,
        const float* __restrict__ att_edge, const float* __restrict__ bias_conv,
        const float* __restrict__ Wout, const float* __restrict__ bout,
        float* __restrict__ vs, float* __restrict__ va, float* __restrict__ vb,
        float* __restrict__ we, float* __restrict__ cb) {
    const int gwid = (blockIdx.x * TPB + threadIdx.x) >> 6;
    const int lane = threadIdx.x & 63;
    if (gwid < 384) {
        int f = gwid;
        float a = 0.f, b = 0.f, c = 0.f;
        for (int k = lane; k < 384; k += 64) {
            float w = Wlin[f * 384 + k];
            a += w * Wout[k];
            b += w * att_src[k];
            c += w * att_dst[k];
        }
        a = wsum64(a); b = wsum64(b); c = wsum64(c);
        if (lane == 0) { vs[f] = a; va[f] = b; vb[f] = c; }
    } else if (gwid < 400) {
        int d = gwid - 384;
        float a = 0.f;
        for (int k = lane; k < 384; k += 64) a += Wedge[d * 384 + k] * att_edge[k];
        a = wsum64(a);
        if (lane == 0) we[d] = a;
    } else if (gwid == 400) {
        float a = 0.f;
        for (int k = lane; k < 384; k += 64) a += bias_conv[k] * Wout[k];
        a = wsum64(a);
        if (lane == 0) cb[0] = a + bout[0];
    }
}

// ---------------------------------------------------------------------------
// K_node: isolated x-stream (measured 13.8 us = 5.6 TB/s in R13). Unchanged.
// ---------------------------------------------------------------------------
__global__ __launch_bounds__(TPB) void k_node(
        const float* __restrict__ x,
        const float* __restrict__ vs, const float* __restrict__ va,
        const float* __restrict__ vb,
        float* __restrict__ s, float* __restrict__ asrc,
        float* __restrict__ adst, int N) {
    const int tid  = threadIdx.x;
    const int ll   = tid & 15;
    const int slot = blockIdx.x * 16 + (tid >> 4);
    const float4* vs4 = (const float4*)vs;
    const float4* va4 = (const float4*)va;
    const float4* vb4 = (const float4*)vb;
    float4 wsr[6], war[6], wbr[6];
#pragma unroll
    for (int j = 0; j < 6; ++j) {
        wsr[j] = vs4[ll + 16 * j];
        war[j] = va4[ll + 16 * j];
        wbr[j] = vb4[ll + 16 * j];
    }
#pragma unroll
    for (int i = 0; i < 4; ++i) {
        int n = slot + i * (NBLK2 * 16);
        if (n < N) {
            const float4* row = (const float4*)(x + (size_t)n * 384);
            float4 xr[6];
#pragma unroll
            for (int j = 0; j < 6; ++j) xr[j] = row[ll + 16 * j];
            float a = 0.f, b = 0.f, c = 0.f;
#pragma unroll
            for (int j = 0; j < 6; ++j) {
                a += xr[j].x*wsr[j].x + xr[j].y*wsr[j].y + xr[j].z*wsr[j].z + xr[j].w*wsr[j].w;
                b += xr[j].x*war[j].x + xr[j].y*war[j].y + xr[j].z*war[j].z + xr[j].w*war[j].w;
                c += xr[j].x*wbr[j].x + xr[j].y*wbr[j].y + xr[j].z*wbr[j].z + xr[j].w*wbr[j].w;
            }
#pragma unroll
            for (int off = 8; off > 0; off >>= 1) {
                a += __shfl_xor(a, off);
                b += __shfl_xor(b, off);
                c += __shfl_xor(c, off);
            }
            if (ll == 0) { s[n] = a; asrc[n] = b; adst[n] = c; }
        }
    }
}

// ---------------------------------------------------------------------------
// K_edge: per-edge ae dot + IN-LDS counting sort; ALL global writes coalesced.
//  1. histogram over dst buckets (LDS atomics, ranks kept in regs)
//  2. Hillis-Steele prefix over 256 counters
//  3. compute ae, scatter record (r<<16|sn, ae) into LDS staging at exact slot
//  4. contiguous flush: rec[eblk*CHUNKCAP + 0..total), 8B/lane coalesced
//  5. cntP[eblk][b] = exclusive prefix (+ total at [256]), coalesced
// Replaces R14's ~200k scattered 8B global stores (the measured ~20us cost,
// partial-line RMW) with 2MB of coalesced stores.
// ---------------------------------------------------------------------------
__global__ __launch_bounds__(TPB) void k_edge(
        const int* __restrict__ src, const int* __restrict__ dst,
        const float* __restrict__ ea, const float* __restrict__ we,
        uint2* __restrict__ rec, int* __restrict__ cntP, int E) {
    __shared__ float weL[16];
    __shared__ int   ldsCnt[NB];     // histogram -> inclusive prefix (in place)
    __shared__ int   ldsOff[NB];     // exclusive prefix
    __shared__ uint2 stage[CHUNKCAP];
    const int tid  = threadIdx.x;
    const int eblk = blockIdx.x;
    if (tid < 16) weL[tid] = we[tid];
    ldsCnt[tid] = 0;
    __syncthreads();

    const int chunk = (E + EBLK - 1) / EBLK;       // 782
    const int ebase = eblk * chunk;
    const int eend  = min(E, ebase + chunk);
    int dnr[ER], rkr[ER], bkr[ER];
#pragma unroll
    for (int r = 0; r < ER; ++r) {
        int e = ebase + r * TPB + tid;
        dnr[r] = -1;
        if (e < eend) {
            int dn = dnr[r] = dst[e];
            int b  = bkr[r] = (int)(((unsigned long long)(unsigned)dn * MAGIC) >> 32);
            rkr[r] = atomicAdd(&ldsCnt[b], 1);     // LDS atomic only
        }
    }
    __syncthreads();
    // Hillis-Steele inclusive scan of ldsCnt (256 threads, 8 steps)
    const int creg = ldsCnt[tid];
#pragma unroll
    for (int d = 1; d < NB; d <<= 1) {
        int v = (tid >= d) ? ldsCnt[tid - d] : 0;
        __syncthreads();
        ldsCnt[tid] += v;
        __syncthreads();
    }
    ldsOff[tid] = ldsCnt[tid] - creg;              // exclusive prefix
    __syncthreads();
    const int total = ldsCnt[NB - 1];

    const float4 w0 = make_float4(weL[0],  weL[1],  weL[2],  weL[3]);
    const float4 w1 = make_float4(weL[4],  weL[5],  weL[6],  weL[7]);
    const float4 w2 = make_float4(weL[8],  weL[9],  weL[10], weL[11]);
    const float4 w3 = make_float4(weL[12], weL[13], weL[14], weL[15]);
#pragma unroll
    for (int r = 0; r < ER; ++r) {
        int dn = dnr[r];
        if (dn >= 0) {
            int e  = ebase + r * TPB + tid;
            int sn = src[e];
            const float4* rw = (const float4*)(ea + (size_t)e * 16);
            float4 v0 = rw[0], v1 = rw[1], v2 = rw[2], v3 = rw[3];
            float a = v0.x*w0.x + v0.y*w0.y + v0.z*w0.z + v0.w*w0.w
                    + v1.x*w1.x + v1.y*w1.y + v1.z*w1.z + v1.w*w1.w
                    + v2.x*w2.x + v2.y*w2.y + v2.z*w2.z + v2.w*w2.w
                    + v3.x*w3.x + v3.y*w3.y + v3.z*w3.z + v3.w*w3.w;
            int b = bkr[r];
            unsigned key = ((unsigned)(dn - b * CNT) << 16) | (unsigned)sn; // sn<65536
            stage[ldsOff[b] + rkr[r]] = make_uint2(key, __float_as_uint(a));
        }
    }
    __syncthreads();
    // coalesced flush of the sorted chunk + prefix table
    uint2* dstc = rec + (size_t)eblk * CHUNKCAP;
    for (int i = tid; i < total; i += TPB) dstc[i] = stage[i];
    cntP[eblk * PSTRIDE + tid] = ldsOff[tid];
    if (tid == 0) cntP[eblk * PSTRIDE + NB] = total;
}

// ---------------------------------------------------------------------------
// K_agg: one block per bucket. Thread t gathers its bucket's mini-run from
// eblk t's sorted chunk (L2/LLC-resident reads, no RMW), gathers asrc/s,
// logit/exp (no segment-max: logits |.|<~25, raw exp fp32-safe, ratio
// unchanged), LDS fp32 aggregation, self-loop epilogue + final output.
// ---------------------------------------------------------------------------
__global__ __launch_bounds__(TPB) void k_agg(
        const uint2* __restrict__ rec, const int* __restrict__ cntP,
        const float* __restrict__ asrc, const float* __restrict__ adst,
        const float* __restrict__ s, const float* __restrict__ cb,
        float* __restrict__ out, int n_nodes) {
    __shared__ float4 accL[CNT];
    __shared__ float  adstL[CNT];
    const int b  = blockIdx.x;
    const int lo = b * CNT;
    int cn = n_nodes - lo;
    if (cn <= 0) return;
    if (cn > CNT) cn = CNT;
    const int tid = threadIdx.x;
    for (int r = tid; r < CNT; r += TPB) accL[r] = make_float4(0.f, 0.f, 0.f, 0.f);
    for (int r = tid; r < cn; r += TPB)  adstL[r] = adst[lo + r];
    __syncthreads();
    const int p0 = cntP[tid * PSTRIDE + b];
    const int p1 = cntP[tid * PSTRIDE + b + 1];    // b=255 -> total at [256]
    const uint2* base = rec + (size_t)tid * CHUNKCAP;
    for (int i = p0; i < p1; ++i) {
        uint2 rc = base[i];
        int r  = (int)(rc.x >> 16);
        int sn = (int)(rc.x & 0xFFFFu);
        float a  = __uint_as_float(rc.y);
        float al = asrc[sn] + adstL[r] + a;
        al = al >= 0.f ? al : NEG_SLOPE * al;
        float ex = __expf(al);
        float* bp = (float*)&accL[r];
        atomicAdd(bp + 0, 1.0f);        // ds_add_f32: deg
        atomicAdd(bp + 1, a);           // aesum
        atomicAdd(bp + 2, ex);          // denom
        atomicAdd(bp + 3, ex * s[sn]);  // num
    }
    __syncthreads();
    const float cbv = cb[0];
    for (int r = tid; r < cn; r += TPB) {
        int n = lo + r;
        float4 ac = accL[r];
        float d  = ac.x < 1.f ? 1.f : ac.x;
        float al = asrc[n] + adstL[r] + ac.y / d;   // self-loop logit (mean ea)
        al = al >= 0.f ? al : NEG_SLOPE * al;
        float ex = __expf(al);
        float v = (ac.w + ex * s[n]) / (ac.z + ex) + cbv;
        out[n] = v > 0.f ? v : 0.f;
    }
}

extern "C" void kernel_launch(void* const* d_in, const int* in_sizes, int n_in,
                              void* d_out, int out_size, void* d_ws, size_t ws_size,
                              hipStream_t stream) {
    const float* x        = (const float*)d_in[0];
    const int*   eidx     = (const int*)d_in[1];
    const float* ea       = (const float*)d_in[2];
    const float* Wlin     = (const float*)d_in[3];
    const float* att_src  = (const float*)d_in[4];
    const float* att_dst  = (const float*)d_in[5];
    const float* Wedge    = (const float*)d_in[6];
    const float* att_edge = (const float*)d_in[7];
    const float* bias_c   = (const float*)d_in[8];
    const float* Wout     = (const float*)d_in[9];
    const float* bout     = (const float*)d_in[10];
    float*       out      = (float*)d_out;

    const int N = in_sizes[0] / 384;   // 50000 (< 65536: sn packs in 16 bits)
    const int E = in_sizes[2] / 16;    // 200000 (<= EBLK*ER*TPB)
    const int* src = eidx;
    const int* dst = eidx + E;

    float* W = (float*)d_ws;
    float* vs   = W;                   // 384
    float* va   = W + 384;             // 384
    float* vb   = W + 768;             // 384
    float* we   = W + 1152;            // 16
    float* cb   = W + 1168;            // 1 (+pad to 1280)
    float* s    = W + 1280;            // N
    float* asrc = s + N;               // N
    float* adst = asrc + N;            // N
    int*   cntP = (int*)(adst + N);                  // EBLK*PSTRIDE ints (266 KB)
    uint2* rec  = (uint2*)(cntP + EBLK * PSTRIDE);   // EBLK*CHUNKCAP uint2 (2 MB)

    // K_fold: folded weight vectors
    k_fold<<<101, TPB, 0, stream>>>(
        Wlin, att_src, att_dst, Wedge, att_edge, bias_c, Wout, bout,
        vs, va, vb, we, cb);
    // K_node: the 76.8 MB x-stream, alone on the machine (13.8 us measured)
    k_node<<<NBLK2, TPB, 0, stream>>>(
        x, vs, va, vb, s, asrc, adst, N);
    // K_edge: in-LDS counting sort, all global writes coalesced
    k_edge<<<EBLK, TPB, 0, stream>>>(
        src, dst, ea, we, rec, cntP, E);
    // K_agg: per-bucket gather of sorted mini-runs + LDS aggregation + epilogue
    k_agg<<<NB, TPB, 0, stream>>>(
        rec, cntP, asrc, adst, s, cb, out, N);
}

// Round 17
// 37.733 us; speedup vs baseline: 1.0600x; 1.0600x over previous
//
#include <hip/hip_runtime.h>

#define NEG_SLOPE 0.2f
#define TPB    256
#define TPB_E  1024             // edge/agg block size: 16 waves/CU at 1 blk/CU
#define NB     256              // dst buckets
#define CNT    196              // nodes per bucket (NB*CNT >= N)
#define EBLK   256              // edge blocks / logical chunks
#define MAGIC  21913099ULL      // ceil(2^32/196): exact d/196 for d < 39M
#define NBLK3  1563             // node blocks: 1563*16 groups x2 sweeps >= 50000
#define CHUNKCAP 1024           // slots per eblk record chunk (>= 782)
#define PSTRIDE  260            // cntP row stride (256 prefixes + total + pad)

__device__ __forceinline__ float wsum64(float v) {
#pragma unroll
    for (int off = 1; off < 64; off <<= 1) v += __shfl_xor(v, off);
    return v;
}

// ---------------------------------------------------------------------------
// K_fold: fold W_lin through W_out/att_src/att_dst (GAT output is linear in
// h -> h never materialized), W_edge through att_edge, bias_conv+b_out.
// ---------------------------------------------------------------------------
__global__ __launch_bounds__(TPB) void k_fold(
        const float* __restrict__ Wlin, const float* __restrict__ att_src,
        const float* __restrict__ att_dst, const float* __restrict__ Wedge,
        const float* __restrict__ att_edge, const float* __restrict__ bias_conv,
        const float* __restrict__ Wout, const float* __restrict__ bout,
        float* __restrict__ vs, float* __restrict__ va, float* __restrict__ vb,
        float* __restrict__ we, float* __restrict__ cb) {
    const int gwid = (blockIdx.x * TPB + threadIdx.x) >> 6;
    const int lane = threadIdx.x & 63;
    if (gwid < 384) {
        int f = gwid;
        float a = 0.f, b = 0.f, c = 0.f;
        for (int k = lane; k < 384; k += 64) {
            float w = Wlin[f * 384 + k];
            a += w * Wout[k];
            b += w * att_src[k];
            c += w * att_dst[k];
        }
        a = wsum64(a); b = wsum64(b); c = wsum64(c);
        if (lane == 0) { vs[f] = a; va[f] = b; vb[f] = c; }
    } else if (gwid < 400) {
        int d = gwid - 384;
        float a = 0.f;
        for (int k = lane; k < 384; k += 64) a += Wedge[d * 384 + k] * att_edge[k];
        a = wsum64(a);
        if (lane == 0) we[d] = a;
    } else if (gwid == 400) {
        float a = 0.f;
        for (int k = lane; k < 384; k += 64) a += bias_conv[k] * Wout[k];
        a = wsum64(a);
        if (lane == 0) cb[0] = a + bout[0];
    }
}

// ---------------------------------------------------------------------------
// K_node: isolated x-stream (13.8 us measured at 782 blocks/4 sweeps in R13).
// Same code, wider grid: 1563 blocks x 2 sweeps -> ~24 waves/CU resident.
// ---------------------------------------------------------------------------
__global__ __launch_bounds__(TPB) void k_node(
        const float* __restrict__ x,
        const float* __restrict__ vs, const float* __restrict__ va,
        const float* __restrict__ vb,
        float* __restrict__ s, float* __restrict__ asrc,
        float* __restrict__ adst, int N) {
    const int tid  = threadIdx.x;
    const int ll   = tid & 15;
    const int slot = blockIdx.x * 16 + (tid >> 4);
    const float4* vs4 = (const float4*)vs;
    const float4* va4 = (const float4*)va;
    const float4* vb4 = (const float4*)vb;
    float4 wsr[6], war[6], wbr[6];
#pragma unroll
    for (int j = 0; j < 6; ++j) {
        wsr[j] = vs4[ll + 16 * j];
        war[j] = va4[ll + 16 * j];
        wbr[j] = vb4[ll + 16 * j];
    }
#pragma unroll
    for (int i = 0; i < 2; ++i) {
        int n = slot + i * (NBLK3 * 16);
        if (n < N) {
            const float4* row = (const float4*)(x + (size_t)n * 384);
            float4 xr[6];
#pragma unroll
            for (int j = 0; j < 6; ++j) xr[j] = row[ll + 16 * j];
            float a = 0.f, b = 0.f, c = 0.f;
#pragma unroll
            for (int j = 0; j < 6; ++j) {
                a += xr[j].x*wsr[j].x + xr[j].y*wsr[j].y + xr[j].z*wsr[j].z + xr[j].w*wsr[j].w;
                b += xr[j].x*war[j].x + xr[j].y*war[j].y + xr[j].z*war[j].z + xr[j].w*war[j].w;
                c += xr[j].x*wbr[j].x + xr[j].y*wbr[j].y + xr[j].z*wbr[j].z + xr[j].w*wbr[j].w;
            }
#pragma unroll
            for (int off = 8; off > 0; off >>= 1) {
                a += __shfl_xor(a, off);
                b += __shfl_xor(b, off);
                c += __shfl_xor(c, off);
            }
            if (ll == 0) { s[n] = a; asrc[n] = b; adst[n] = c; }
        }
    }
}

// ---------------------------------------------------------------------------
// K_edge: 1024 threads/block, ONE edge per thread (chunk=782<=1024), 16
// waves/CU (was 4 -> latency-bound, R15 lesson). In-LDS counting sort,
// coalesced flush + prefix table. LDS atomics only.
// ---------------------------------------------------------------------------
__global__ __launch_bounds__(TPB_E) void k_edge(
        const int* __restrict__ src, const int* __restrict__ dst,
        const float* __restrict__ ea, const float* __restrict__ we,
        uint2* __restrict__ rec, int* __restrict__ cntP, int E) {
    __shared__ float weL[16];
    __shared__ int   ldsCnt[NB];     // histogram -> inclusive prefix (in place)
    __shared__ int   ldsOff[NB];     // exclusive prefix
    __shared__ uint2 stage[CHUNKCAP];
    const int tid  = threadIdx.x;
    const int eblk = blockIdx.x;
    if (tid < 16) weL[tid] = we[tid];
    if (tid < NB) ldsCnt[tid] = 0;
    __syncthreads();

    const int chunk = (E + EBLK - 1) / EBLK;       // 782 (<= TPB_E)
    const int ebase = eblk * chunk;
    const int eend  = min(E, ebase + chunk);
    const int e     = ebase + tid;
    const bool valid = e < eend;
    int dn = 0, bk = 0, rk = 0;
    if (valid) {
        dn = dst[e];
        bk = (int)(((unsigned long long)(unsigned)dn * MAGIC) >> 32);
        rk = atomicAdd(&ldsCnt[bk], 1);            // LDS atomic only
    }
    __syncthreads();
    // Hillis-Steele inclusive scan of the 256 counters (uniform barriers)
    const int creg = (tid < NB) ? ldsCnt[tid] : 0;
#pragma unroll
    for (int d = 1; d < NB; d <<= 1) {
        int v = (tid >= d && tid < NB) ? ldsCnt[tid - d] : 0;
        __syncthreads();
        if (tid < NB) ldsCnt[tid] += v;
        __syncthreads();
    }
    if (tid < NB) ldsOff[tid] = ldsCnt[tid] - creg;
    __syncthreads();
    const int total = ldsCnt[NB - 1];

    if (valid) {
        const int sn = src[e];
        const float4* rw = (const float4*)(ea + (size_t)e * 16);
        const float4 w0 = make_float4(weL[0],  weL[1],  weL[2],  weL[3]);
        const float4 w1 = make_float4(weL[4],  weL[5],  weL[6],  weL[7]);
        const float4 w2 = make_float4(weL[8],  weL[9],  weL[10], weL[11]);
        const float4 w3 = make_float4(weL[12], weL[13], weL[14], weL[15]);
        float4 v0 = rw[0], v1 = rw[1], v2 = rw[2], v3 = rw[3];
        float a = v0.x*w0.x + v0.y*w0.y + v0.z*w0.z + v0.w*w0.w
                + v1.x*w1.x + v1.y*w1.y + v1.z*w1.z + v1.w*w1.w
                + v2.x*w2.x + v2.y*w2.y + v2.z*w2.z + v2.w*w2.w
                + v3.x*w3.x + v3.y*w3.y + v3.z*w3.z + v3.w*w3.w;
        unsigned key = ((unsigned)(dn - bk * CNT) << 16) | (unsigned)sn;  // sn<65536
        stage[ldsOff[bk] + rk] = make_uint2(key, __float_as_uint(a));
    }
    __syncthreads();
    // coalesced flush (one round: total <= 782 <= TPB_E) + prefix table
    uint2* dstc = rec + (size_t)eblk * CHUNKCAP;
    if (tid < total) dstc[tid] = stage[tid];
    if (tid < NB) cntP[eblk * PSTRIDE + tid] = ldsOff[tid];
    if (tid == 0) cntP[eblk * PSTRIDE + NB] = total;
}

// ---------------------------------------------------------------------------
// K_agg: 1024 threads/block (16 waves/CU). Thread t = (quarter q=t>>8,
// eblk=t&255) walks its bucket's mini-run with stride 4 -> 4x the
// parallelism of R15 and 1/4 the dependent-gather chain depth. LDS fp32
// aggregation, self-loop epilogue + final output. No segment-max (logits
// |.|<~25, raw exp fp32-safe, softmax ratio unchanged).
// ---------------------------------------------------------------------------
__global__ __launch_bounds__(TPB_E) void k_agg(
        const uint2* __restrict__ rec, const int* __restrict__ cntP,
        const float* __restrict__ asrc, const float* __restrict__ adst,
        const float* __restrict__ s, const float* __restrict__ cb,
        float* __restrict__ out, int n_nodes) {
    __shared__ float4 accL[CNT];
    __shared__ float  adstL[CNT];
    const int b  = blockIdx.x;
    const int lo = b * CNT;
    int cn = n_nodes - lo;
    if (cn <= 0) return;
    if (cn > CNT) cn = CNT;
    const int tid = threadIdx.x;
    for (int r = tid; r < CNT; r += TPB_E) accL[r] = make_float4(0.f, 0.f, 0.f, 0.f);
    for (int r = tid; r < cn; r += TPB_E)  adstL[r] = adst[lo + r];
    __syncthreads();
    const int eblk = tid & (NB - 1);
    const int q    = tid >> 8;                     // 0..3
    const int p0 = cntP[eblk * PSTRIDE + b];
    const int p1 = cntP[eblk * PSTRIDE + b + 1];   // b=255 -> total at [256]
    const uint2* base = rec + (size_t)eblk * CHUNKCAP;
    for (int i = p0 + q; i < p1; i += 4) {
        uint2 rc = base[i];
        int r  = (int)(rc.x >> 16);
        int sn = (int)(rc.x & 0xFFFFu);
        float a  = __uint_as_float(rc.y);
        float al = asrc[sn] + adstL[r] + a;
        al = al >= 0.f ? al : NEG_SLOPE * al;
        float ex = __expf(al);
        float* bp = (float*)&accL[r];
        atomicAdd(bp + 0, 1.0f);        // ds_add_f32: deg
        atomicAdd(bp + 1, a);           // aesum
        atomicAdd(bp + 2, ex);          // denom
        atomicAdd(bp + 3, ex * s[sn]);  // num
    }
    __syncthreads();
    const float cbv = cb[0];
    for (int r = tid; r < cn; r += TPB_E) {
        int n = lo + r;
        float4 ac = accL[r];
        float d  = ac.x < 1.f ? 1.f : ac.x;
        float al = asrc[n] + adstL[r] + ac.y / d;   // self-loop logit (mean ea)
        al = al >= 0.f ? al : NEG_SLOPE * al;
        float ex = __expf(al);
        float v = (ac.w + ex * s[n]) / (ac.z + ex) + cbv;
        out[n] = v > 0.f ? v : 0.f;
    }
}

extern "C" void kernel_launch(void* const* d_in, const int* in_sizes, int n_in,
                              void* d_out, int out_size, void* d_ws, size_t ws_size,
                              hipStream_t stream) {
    const float* x        = (const float*)d_in[0];
    const int*   eidx     = (const int*)d_in[1];
    const float* ea       = (const float*)d_in[2];
    const float* Wlin     = (const float*)d_in[3];
    const float* att_src  = (const float*)d_in[4];
    const float* att_dst  = (const float*)d_in[5];
    const float* Wedge    = (const float*)d_in[6];
    const float* att_edge = (const float*)d_in[7];
    const float* bias_c   = (const float*)d_in[8];
    const float* Wout     = (const float*)d_in[9];
    const float* bout     = (const float*)d_in[10];
    float*       out      = (float*)d_out;

    const int N = in_sizes[0] / 384;   // 50000 (< 65536: sn packs in 16 bits)
    const int E = in_sizes[2] / 16;    // 200000 (chunk 782 <= 1024)
    const int* src = eidx;
    const int* dst = eidx + E;

    float* W = (float*)d_ws;
    float* vs   = W;                   // 384
    float* va   = W + 384;             // 384
    float* vb   = W + 768;             // 384
    float* we   = W + 1152;            // 16
    float* cb   = W + 1168;            // 1 (+pad to 1280)
    float* s    = W + 1280;            // N
    float* asrc = s + N;               // N
    float* adst = asrc + N;            // N
    int*   cntP = (int*)(adst + N);                  // EBLK*PSTRIDE ints (266 KB)
    uint2* rec  = (uint2*)(cntP + EBLK * PSTRIDE);   // EBLK*CHUNKCAP uint2 (2 MB)

    // K_fold: folded weight vectors
    k_fold<<<101, TPB, 0, stream>>>(
        Wlin, att_src, att_dst, Wedge, att_edge, bias_c, Wout, bout,
        vs, va, vb, we, cb);
    // K_node: the 76.8 MB x-stream, alone on the machine, wider grid
    k_node<<<NBLK3, TPB, 0, stream>>>(
        x, vs, va, vb, s, asrc, adst, N);
    // K_edge: in-LDS counting sort at 16 waves/CU (one edge per thread)
    k_edge<<<EBLK, TPB_E, 0, stream>>>(
        src, dst, ea, we, rec, cntP, E);
    // K_agg: per-bucket gather at 16 waves/CU (4-way split mini-runs)
    k_agg<<<NB, TPB_E, 0, stream>>>(
        rec, cntP, asrc, adst, s, cb, out, N);
}